// Round 2
// baseline (2414.515 us; speedup 1.0000x reference)
//
#include <hip/hip_runtime.h>

#define TT 4096
#define DPROJ 800000

typedef float v2f __attribute__((ext_vector_type(2)));
typedef float v4f __attribute__((ext_vector_type(4)));

__device__ __forceinline__ float fexp2(float x) { return __builtin_amdgcn_exp2f(x); }
__device__ __forceinline__ float frcp(float x) { return __builtin_amdgcn_rcpf(x); }

__device__ __forceinline__ v2f pkfma(v2f a, v2f b, v2f c) {
    asm("v_pk_fma_f32 %0, %1, %2, %0" : "+v"(c) : "v"(a), "v"(b));
    return c;
}

template <int CTRL>
__device__ __forceinline__ float dppf(float x) {
    return __int_as_float(
        __builtin_amdgcn_update_dpp(0, __float_as_int(x), CTRL, 0xF, 0xF, true));
}

__device__ __forceinline__ v2f lo2(v4f v) { return __builtin_shufflevector(v, v, 0, 1); }
__device__ __forceinline__ v2f hi2(v4f v) { return __builtin_shufflevector(v, v, 2, 3); }

// barrier WITHOUT the vmcnt(0) drain __syncthreads would emit.
__device__ __forceinline__ void barrier_nd() {
    asm volatile("s_waitcnt lgkmcnt(0)\n\ts_barrier" ::: "memory");
}

// ---- named-register bundles (NO allocas -> NO scratch) ----
#define WDECL(nm) v2f nm##0, nm##1, nm##2, nm##3, nm##4, nm##5, nm##6, nm##7;
#define WLOAD(nm, base)                                                      \
    {                                                                        \
        const v4f* q_ = (const v4f*)(base);                                  \
        v4f A_ = q_[0], B_ = q_[1], C_ = q_[2], D_ = q_[3];                  \
        nm##0 = lo2(A_); nm##1 = hi2(A_); nm##2 = lo2(B_); nm##3 = hi2(B_);  \
        nm##4 = lo2(C_); nm##5 = hi2(C_); nm##6 = lo2(D_); nm##7 = hi2(D_);  \
    }
#define WDOT(acc, nm, h)                                                     \
    acc = pkfma(nm##0, h##0, acc); acc = pkfma(nm##1, h##1, acc);            \
    acc = pkfma(nm##2, h##2, acc); acc = pkfma(nm##3, h##3, acc);            \
    acc = pkfma(nm##4, h##4, acc); acc = pkfma(nm##5, h##5, acc);            \
    acc = pkfma(nm##6, h##6, acc); acc = pkfma(nm##7, h##7, acc);
#define HREAD(h, ptr)                                                        \
    v2f h##0, h##1, h##2, h##3, h##4, h##5, h##6, h##7;                      \
    {                                                                        \
        const v4f* p_ = (const v4f*)(ptr);                                   \
        v4f ha_ = p_[0], hb_ = p_[1], hc_ = p_[2], hd_ = p_[3];              \
        h##0 = lo2(ha_); h##1 = hi2(ha_); h##2 = lo2(hb_); h##3 = hi2(hb_);  \
        h##4 = lo2(hc_); h##5 = hi2(hc_); h##6 = lo2(hd_); h##7 = hi2(hd_);  \
    }

// Anti-rematerialization keep-alive: turn the weight values into inline-asm
// defs each outer iteration.  The pre-RA remat stage can re-sink invariant
// global LOADS into the loop (that was the VGPR=92 / per-step-L2-reload
// failure mode), but it cannot rematerialize an INLINEASM def -> the
// allocator must keep these live in VGPRs across the loop.
#define KEEP8(nm)                                                            \
    asm volatile("" : "+v"(nm##0), "+v"(nm##1), "+v"(nm##2), "+v"(nm##3),    \
                      "+v"(nm##4), "+v"(nm##5), "+v"(nm##6), "+v"(nm##7));

// Kernel 1: gx0p[t*256 + u*4 + g] = dot(x[t,:], w_ih0[g*64+u,:]) + b_ih0 + b_hh0
__global__ __launch_bounds__(256) void gx0_kernel(const float* __restrict__ x,
                                                  const float* __restrict__ w_ih0,
                                                  const float* __restrict__ b_ih0,
                                                  const float* __restrict__ b_hh0,
                                                  float* __restrict__ gx0p) {
    __shared__ __align__(16) float xs[32];
    const int t = blockIdx.x;
    const int j = threadIdx.x;
    if (j < 32) xs[j] = x[t * 32 + j];
    __syncthreads();
    const float4* w4 = (const float4*)(w_ih0 + j * 32);
    const float4* x4 = (const float4*)xs;
    float acc = b_ih0[j] + b_hh0[j];
#pragma unroll
    for (int u = 0; u < 8; ++u) {
        float4 w = w4[u];
        float4 xv = x4[u];
        acc += w.x * xv.x + w.y * xv.y + w.z * xv.z + w.w * xv.w;
    }
    const int g = j >> 6;
    const int uu = j & 63;
    gx0p[t * 256 + uu * 4 + g] = acc;
}

// Kernel 2: sequential 2-layer LSTM. 512 threads = 8 waves on 1 CU.
// Waves 0-3 (A): layer0 time i.  Waves 4-7 (B): layer1 time i-1.
// Lane (u = j>>2, q = j&3): all 4 gate rows of unit u over k in [16q,16q+16).
// __launch_bounds__(512, 2): min 2 waves/EU -> 256-VGPR budget, so the
// ~200 live weight values (B: 128 floats of weights + h/k/acc) can stay
// register-resident.  Round-0 measured VGPR=92 -> per-step weight reload
// from L2 at ~128B/cy/CU == the entire 475ns step time.  KEEP8 blocks
// load-remat so the allocator cannot sink the weight loads back into the
// loop.  (NOTE: do NOT also add amdgpu_waves_per_eu — duplicated occupancy
// attrs were the only novel toolchain input in the round-1 container
// failure.)
__global__ __launch_bounds__(512, 2)
void lstm_kernel(const float* __restrict__ gx0,
                 const float* __restrict__ w_hh0,
                 const float* __restrict__ w_ih1,
                 const float* __restrict__ w_hh1,
                 const float* __restrict__ b_ih1,
                 const float* __restrict__ b_hh1,
                 float* __restrict__ hc_out) {
    __shared__ __align__(16) float h0buf[2][64];
    __shared__ __align__(16) float h1buf[2][64];

    const int t = threadIdx.x;
    const int j = t & 255;
    const int u = j >> 2;
    const int q = j & 3;
    const int qk = q * 16;
    const bool qg = (q == 2);
    const float kmul = qg ? -2.885390082f : -1.442695041f;
    const float mm = qg ? 2.0f : 1.0f;
    const float dd = qg ? 1.0f : 0.0f;
    const v2f Z2 = {0.0f, 0.0f};
    float cst = 0.0f;

    if (t < 256) {
        // ================= group A: layer 0 =================
        WDECL(wA0_) WDECL(wA1_) WDECL(wA2_) WDECL(wA3_)
        WLOAD(wA0_, w_hh0 + (0 * 64 + u) * 64 + qk)
        WLOAD(wA1_, w_hh0 + (1 * 64 + u) * 64 + qk)
        WLOAD(wA2_, w_hh0 + (2 * 64 + u) * 64 + qk)
        WLOAD(wA3_, w_hh0 + (3 * 64 + u) * 64 + qk)
        const float4* gp = ((const float4*)gx0) + u;
        float4 pf0 = gp[0 * 64];
        float4 pf1 = gp[1 * 64];
        float4 pf2 = gp[2 * 64];
        float4 pf3 = gp[3 * 64];
        if (q == 0) h0buf[1][u] = 0.0f;
        barrier_nd();  // init visible

#define A_STEP(PF, RDP, WRP, ROWI)                                                      \
    {                                                                                   \
        HREAD(h_, &h0buf[RDP][qk])                                                      \
        v2f a0 = Z2, a1 = Z2, a2 = Z2, a3 = Z2;                                         \
        WDOT(a0, wA0_, h_) WDOT(a1, wA1_, h_) WDOT(a2, wA2_, h_) WDOT(a3, wA3_, h_)     \
        float G0 = a0.x + a0.y, G1 = a1.x + a1.y, G2 = a2.x + a2.y, G3 = a3.x + a3.y;   \
        G0 += dppf<0xB1>(G0); G1 += dppf<0xB1>(G1);                                     \
        G2 += dppf<0xB1>(G2); G3 += dppf<0xB1>(G3);                                     \
        G0 += dppf<0x4E>(G0); G1 += dppf<0x4E>(G1);                                     \
        G2 += dppf<0x4E>(G2); G3 += dppf<0x4E>(G3);                                     \
        G0 += PF.x; G1 += PF.y; G2 += PF.z; G3 += PF.w;                                 \
        float arg = q == 0 ? G0 : (q == 1 ? G1 : (q == 2 ? G2 : G3));                   \
        float act = __builtin_fmaf(mm, frcp(1.0f + fexp2(kmul * arg)), -dd);            \
        float gi = dppf<0x00>(act), gf = dppf<0x55>(act);                               \
        float gg = dppf<0xAA>(act), go = dppf<0xFF>(act);                               \
        cst = __builtin_fmaf(gf, cst, gi * gg);                                         \
        float th = __builtin_fmaf(2.0f, frcp(1.0f + fexp2(-2.885390082f * cst)), -1.0f);\
        float hnew = go * th;                                                           \
        if (q == 0) h0buf[WRP][u] = hnew;                                               \
        PF = gp[(ROWI) * 64];                                                           \
        barrier_nd();                                                                   \
    }

        A_STEP(pf0, 1, 0, 4)  // i = 0
#pragma unroll 1
        for (int b = 0; b < 1023; ++b) {  // i = 4b+1 .. 4b+4
            KEEP8(wA0_) KEEP8(wA1_) KEEP8(wA2_) KEEP8(wA3_)
            const int i4 = 4 * b;
            A_STEP(pf1, 0, 1, i4 + 5)
            A_STEP(pf2, 1, 0, i4 + 6)
            A_STEP(pf3, 0, 1, i4 + 7)
            A_STEP(pf0, 1, 0, (i4 + 8 < TT ? i4 + 8 : TT - 1))
        }
        A_STEP(pf1, 0, 1, TT - 1)  // i = 4093
        A_STEP(pf2, 1, 0, TT - 1)  // i = 4094
        A_STEP(pf3, 0, 1, TT - 1)  // i = 4095
        barrier_nd();              // i = 4096 (B-only step)
    } else {
        // ================= group B: layer 1 =================
        WDECL(wi0_) WDECL(wi1_) WDECL(wi2_) WDECL(wi3_)
        WDECL(wh0_) WDECL(wh1_) WDECL(wh2_) WDECL(wh3_)
        WLOAD(wi0_, w_ih1 + (0 * 64 + u) * 64 + qk)
        WLOAD(wi1_, w_ih1 + (1 * 64 + u) * 64 + qk)
        WLOAD(wi2_, w_ih1 + (2 * 64 + u) * 64 + qk)
        WLOAD(wi3_, w_ih1 + (3 * 64 + u) * 64 + qk)
        WLOAD(wh0_, w_hh1 + (0 * 64 + u) * 64 + qk)
        WLOAD(wh1_, w_hh1 + (1 * 64 + u) * 64 + qk)
        WLOAD(wh2_, w_hh1 + (2 * 64 + u) * 64 + qk)
        WLOAD(wh3_, w_hh1 + (3 * 64 + u) * 64 + qk)
        float4 bias;
        bias.x = b_ih1[0 * 64 + u] + b_hh1[0 * 64 + u];
        bias.y = b_ih1[1 * 64 + u] + b_hh1[1 * 64 + u];
        bias.z = b_ih1[2 * 64 + u] + b_hh1[2 * 64 + u];
        bias.w = b_ih1[3 * 64 + u] + b_hh1[3 * 64 + u];
        float hlast = 0.0f;
        if (q == 0) h1buf[1][u] = 0.0f;
        barrier_nd();  // pairs with A init barrier
        barrier_nd();  // pairs with A's i=0 step

#define B_STEP(P)                                                                       \
    {                                                                                   \
        HREAD(h_, &h0buf[P][qk])                                                        \
        HREAD(k_, &h1buf[(P) ^ 1][qk])                                                  \
        v2f a0 = Z2, a1 = Z2, a2 = Z2, a3 = Z2;                                         \
        v2f c0 = Z2, c1 = Z2, c2 = Z2, c3 = Z2;                                         \
        WDOT(a0, wi0_, h_) WDOT(a1, wi1_, h_) WDOT(a2, wi2_, h_) WDOT(a3, wi3_, h_)     \
        WDOT(c0, wh0_, k_) WDOT(c1, wh1_, k_) WDOT(c2, wh2_, k_) WDOT(c3, wh3_, k_)     \
        float G0 = (a0.x + a0.y) + (c0.x + c0.y);                                       \
        float G1 = (a1.x + a1.y) + (c1.x + c1.y);                                       \
        float G2 = (a2.x + a2.y) + (c2.x + c2.y);                                       \
        float G3 = (a3.x + a3.y) + (c3.x + c3.y);                                       \
        G0 += dppf<0xB1>(G0); G1 += dppf<0xB1>(G1);                                     \
        G2 += dppf<0xB1>(G2); G3 += dppf<0xB1>(G3);                                     \
        G0 += dppf<0x4E>(G0); G1 += dppf<0x4E>(G1);                                     \
        G2 += dppf<0x4E>(G2); G3 += dppf<0x4E>(G3);                                     \
        G0 += bias.x; G1 += bias.y; G2 += bias.z; G3 += bias.w;                         \
        float arg = q == 0 ? G0 : (q == 1 ? G1 : (q == 2 ? G2 : G3));                   \
        float act = __builtin_fmaf(mm, frcp(1.0f + fexp2(kmul * arg)), -dd);            \
        float gi = dppf<0x00>(act), gf = dppf<0x55>(act);                               \
        float gg = dppf<0xAA>(act), go = dppf<0xFF>(act);                               \
        cst = __builtin_fmaf(gf, cst, gi * gg);                                         \
        float th = __builtin_fmaf(2.0f, frcp(1.0f + fexp2(-2.885390082f * cst)), -1.0f);\
        float hnew = go * th;                                                           \
        hlast = hnew;                                                                   \
        if (q == 0) h1buf[P][u] = hnew;                                                 \
        barrier_nd();                                                                   \
    }

#pragma unroll 1
        for (int b = 0; b < 1023; ++b) {
            KEEP8(wi0_) KEEP8(wi1_) KEEP8(wi2_) KEEP8(wi3_)
            KEEP8(wh0_) KEEP8(wh1_) KEEP8(wh2_) KEEP8(wh3_)
            asm volatile("" : "+v"(bias.x), "+v"(bias.y), "+v"(bias.z), "+v"(bias.w));
            B_STEP(0)
            B_STEP(1)
            B_STEP(0)
            B_STEP(1)
        }
        B_STEP(0)  // i = 4093
        B_STEP(1)  // i = 4094
        B_STEP(0)  // i = 4095
        B_STEP(1)  // i = 4096 -> h1_4095 (final)
        if (q == 0) {
            hc_out[u] = hlast;
            hc_out[64 + u] = cst;
        }
    }
}

// Kernel 3: out[0..800000) = c1 @ w_es.T + b_es ; out[800000..1.6M) = h1 @ w_eh.T + b_eh
__global__ __launch_bounds__(256) void proj_kernel(const float* __restrict__ hc,
                                                   const float* __restrict__ w_es,
                                                   const float* __restrict__ b_es,
                                                   const float* __restrict__ w_eh,
                                                   const float* __restrict__ b_eh,
                                                   float* __restrict__ out) {
    __shared__ __align__(16) float hv[64];
    __shared__ __align__(16) float cv[64];
    const int tid = threadIdx.x;
    if (tid < 64) hv[tid] = hc[tid];
    else if (tid < 128) cv[tid - 64] = hc[tid];
    __syncthreads();

    const int p = tid & 3;
    const long r = (long)blockIdx.x * 64 + (tid >> 2);
    const float* w;
    const float* bb;
    const float* v;
    long rr;
    if (r < DPROJ) {
        rr = r;
        w = w_es;
        bb = b_es;
        v = cv;
    } else {
        rr = r - DPROJ;
        w = w_eh;
        bb = b_eh;
        v = hv;
    }
    const float4* wp = (const float4*)(w + rr * 64 + p * 16);
    const float4* vp = (const float4*)(v + p * 16);
    v2f s = {0.0f, 0.0f};
#pragma unroll
    for (int cc = 0; cc < 4; ++cc) {
        float4 wv = wp[cc];
        float4 vv = vp[cc];
        v2f w01 = {wv.x, wv.y}, v01 = {vv.x, vv.y};
        v2f w23 = {wv.z, wv.w}, v23 = {vv.z, vv.w};
        s = pkfma(w01, v01, s);
        s = pkfma(w23, v23, s);
    }
    float sum = s.x + s.y;
    sum += dppf<0xB1>(sum);
    sum += dppf<0x4E>(sum);
    if (p == 0) out[r] = sum + bb[rr];
}

extern "C" void kernel_launch(void* const* d_in, const int* in_sizes, int n_in,
                              void* d_out, int out_size, void* d_ws, size_t ws_size,
                              hipStream_t stream) {
    const float* x = (const float*)d_in[0];
    const float* w_ih0 = (const float*)d_in[1];
    const float* w_hh0 = (const float*)d_in[2];
    const float* b_ih0 = (const float*)d_in[3];
    const float* b_hh0 = (const float*)d_in[4];
    const float* w_ih1 = (const float*)d_in[5];
    const float* w_hh1 = (const float*)d_in[6];
    const float* b_ih1 = (const float*)d_in[7];
    const float* b_hh1 = (const float*)d_in[8];
    const float* w_eh = (const float*)d_in[9];
    const float* b_eh = (const float*)d_in[10];
    const float* w_es = (const float*)d_in[11];
    const float* b_es = (const float*)d_in[12];
    float* out = (float*)d_out;

    float* gx0 = (float*)d_ws;     // 4096*256 floats = 4 MB (permuted float4-per-unit)
    float* hc = gx0 + 4096 * 256;  // 128 floats: [h1(64), c1(64)]

    gx0_kernel<<<4096, 256, 0, stream>>>(x, w_ih0, b_ih0, b_hh0, gx0);
    lstm_kernel<<<1, 512, 0, stream>>>(gx0, w_hh0, w_ih1, w_hh1, b_ih1, b_hh1, hc);
    proj_kernel<<<2 * DPROJ / 64, 256, 0, stream>>>(hc, w_es, b_es, w_eh, b_eh, out);
}

// Round 3
// 2355.490 us; speedup vs baseline: 1.0251x; 1.0251x over previous
//
#include <hip/hip_runtime.h>

#define TT 4096
#define DPROJ 800000

typedef float v2f __attribute__((ext_vector_type(2)));
typedef float v4f __attribute__((ext_vector_type(4)));

__device__ __forceinline__ float fexp2(float x) { return __builtin_amdgcn_exp2f(x); }
__device__ __forceinline__ float frcp(float x) { return __builtin_amdgcn_rcpf(x); }

__device__ __forceinline__ v2f pkfma(v2f a, v2f b, v2f c) {
    asm("v_pk_fma_f32 %0, %1, %2, %0" : "+v"(c) : "v"(a), "v"(b));
    return c;
}

template <int CTRL>
__device__ __forceinline__ float dppf(float x) {
    return __int_as_float(
        __builtin_amdgcn_update_dpp(0, __float_as_int(x), CTRL, 0xF, 0xF, true));
}

__device__ __forceinline__ v2f lo2(v4f v) { return __builtin_shufflevector(v, v, 0, 1); }
__device__ __forceinline__ v2f hi2(v4f v) { return __builtin_shufflevector(v, v, 2, 3); }

// barrier WITHOUT the vmcnt(0) drain __syncthreads would emit.
__device__ __forceinline__ void barrier_nd() {
    asm volatile("s_waitcnt lgkmcnt(0)\n\ts_barrier" ::: "memory");
}

// ---- named-register bundles (NO allocas -> NO scratch) ----
#define WDECL(nm) v2f nm##0, nm##1, nm##2, nm##3, nm##4, nm##5, nm##6, nm##7;
#define WLOAD(nm, base)                                                      \
    {                                                                        \
        const v4f* q_ = (const v4f*)(base);                                  \
        v4f A_ = q_[0], B_ = q_[1], C_ = q_[2], D_ = q_[3];                  \
        nm##0 = lo2(A_); nm##1 = hi2(A_); nm##2 = lo2(B_); nm##3 = hi2(B_);  \
        nm##4 = lo2(C_); nm##5 = hi2(C_); nm##6 = lo2(D_); nm##7 = hi2(D_);  \
    }
#define WDOT(acc, nm, h)                                                     \
    acc = pkfma(nm##0, h##0, acc); acc = pkfma(nm##1, h##1, acc);            \
    acc = pkfma(nm##2, h##2, acc); acc = pkfma(nm##3, h##3, acc);            \
    acc = pkfma(nm##4, h##4, acc); acc = pkfma(nm##5, h##5, acc);            \
    acc = pkfma(nm##6, h##6, acc); acc = pkfma(nm##7, h##7, acc);
#define HREAD(h, ptr)                                                        \
    v2f h##0, h##1, h##2, h##3, h##4, h##5, h##6, h##7;                      \
    {                                                                        \
        const v4f* p_ = (const v4f*)(ptr);                                   \
        v4f ha_ = p_[0], hb_ = p_[1], hc_ = p_[2], hd_ = p_[3];              \
        h##0 = lo2(ha_); h##1 = hi2(ha_); h##2 = lo2(hb_); h##3 = hi2(hb_);  \
        h##4 = lo2(hc_); h##5 = hi2(hc_); h##6 = lo2(hd_); h##7 = hi2(hd_);  \
    }

// Anti-rematerialization keep-alive (zero-cost once regs are available).
#define KEEP8(nm)                                                            \
    asm volatile("" : "+v"(nm##0), "+v"(nm##1), "+v"(nm##2), "+v"(nm##3),    \
                      "+v"(nm##4), "+v"(nm##5), "+v"(nm##6), "+v"(nm##7));

// Kernel 1: gx0p[t*256 + u*4 + g] = dot(x[t,:], w_ih0[g*64+u,:]) + b_ih0 + b_hh0
__global__ __launch_bounds__(256) void gx0_kernel(const float* __restrict__ x,
                                                  const float* __restrict__ w_ih0,
                                                  const float* __restrict__ b_ih0,
                                                  const float* __restrict__ b_hh0,
                                                  float* __restrict__ gx0p) {
    __shared__ __align__(16) float xs[32];
    const int t = blockIdx.x;
    const int j = threadIdx.x;
    if (j < 32) xs[j] = x[t * 32 + j];
    __syncthreads();
    const float4* w4 = (const float4*)(w_ih0 + j * 32);
    const float4* x4 = (const float4*)xs;
    float acc = b_ih0[j] + b_hh0[j];
#pragma unroll
    for (int u = 0; u < 8; ++u) {
        float4 w = w4[u];
        float4 xv = x4[u];
        acc += w.x * xv.x + w.y * xv.y + w.z * xv.z + w.w * xv.w;
    }
    const int g = j >> 6;
    const int uu = j & 63;
    gx0p[t * 256 + uu * 4 + g] = acc;
}

// Kernel 2: sequential 2-layer LSTM. 512 threads = 8 waves on 1 CU.
// Waves 0-3 (A): layer0 time i.  Waves 4-7 (B): layer1 time i-1.
// Lane (u = j>>2, q = j&3): all 4 gate rows of unit u over k in [16q,16q+16).
//
// OCCUPANCY CAP VIA LDS (round-3 lever): natural live set in branch B is
// ~176 VGPRs (128 weight regs + h/k/acc).  The backend's pre-RA pressure
// reduction remats/sinks weight-load bundles into the step loop to chase a
// higher occupancy target — observed VGPR=88..92 = 176 minus ~5 sunk
// 16-reg bundles, i.e. ~80KB/step reloaded from L2 ≈ 600+ cy/step, the gap
// between ~500cy compute+sync and the measured ~1140cy/step.  BOTH
// attribute knobs (amdgpu_waves_per_eu(2,2), __launch_bounds__(512,2))
// failed to move the allocation.  LDS occupancy is a PHYSICAL constraint
// the scheduler cannot reduce: a 96 KiB static pool -> only 1 workgroup
// (8 waves = 2/EU) fits per CU -> register budget 256 -> nothing to chase,
// weights stay resident.  Pool costs nothing at runtime (grid = 1 block).
__global__ __launch_bounds__(512, 2)
void lstm_kernel(const float* __restrict__ gx0,
                 const float* __restrict__ w_hh0,
                 const float* __restrict__ w_ih1,
                 const float* __restrict__ w_hh1,
                 const float* __restrict__ b_ih1,
                 const float* __restrict__ b_hh1,
                 float* __restrict__ hc_out) {
    // 24576 floats = 96 KiB: 2 WGs would need 192 KiB > 160 KiB/CU -> 1 WG/CU.
    __shared__ __align__(16) float lds_pool[24576];
    float(*h0buf)[64] = (float(*)[64])(lds_pool);        // [2][64]
    float(*h1buf)[64] = (float(*)[64])(lds_pool + 128);  // [2][64]

    const int t = threadIdx.x;
    const int j = t & 255;
    const int u = j >> 2;
    const int q = j & 3;
    const int qk = q * 16;
    const bool qg = (q == 2);
    const float kmul = qg ? -2.885390082f : -1.442695041f;
    const float mm = qg ? 2.0f : 1.0f;
    const float dd = qg ? 1.0f : 0.0f;
    const v2f Z2 = {0.0f, 0.0f};
    float cst = 0.0f;

    if (t < 256) {
        // ================= group A: layer 0 =================
        WDECL(wA0_) WDECL(wA1_) WDECL(wA2_) WDECL(wA3_)
        WLOAD(wA0_, w_hh0 + (0 * 64 + u) * 64 + qk)
        WLOAD(wA1_, w_hh0 + (1 * 64 + u) * 64 + qk)
        WLOAD(wA2_, w_hh0 + (2 * 64 + u) * 64 + qk)
        WLOAD(wA3_, w_hh0 + (3 * 64 + u) * 64 + qk)
        const float4* gp = ((const float4*)gx0) + u;
        float4 pf0 = gp[0 * 64];
        float4 pf1 = gp[1 * 64];
        float4 pf2 = gp[2 * 64];
        float4 pf3 = gp[3 * 64];
        if (q == 0) h0buf[1][u] = 0.0f;
        barrier_nd();  // init visible

#define A_STEP(PF, RDP, WRP, ROWI)                                                      \
    {                                                                                   \
        HREAD(h_, &h0buf[RDP][qk])                                                      \
        v2f a0 = Z2, a1 = Z2, a2 = Z2, a3 = Z2;                                         \
        WDOT(a0, wA0_, h_) WDOT(a1, wA1_, h_) WDOT(a2, wA2_, h_) WDOT(a3, wA3_, h_)     \
        float G0 = a0.x + a0.y, G1 = a1.x + a1.y, G2 = a2.x + a2.y, G3 = a3.x + a3.y;   \
        G0 += dppf<0xB1>(G0); G1 += dppf<0xB1>(G1);                                     \
        G2 += dppf<0xB1>(G2); G3 += dppf<0xB1>(G3);                                     \
        G0 += dppf<0x4E>(G0); G1 += dppf<0x4E>(G1);                                     \
        G2 += dppf<0x4E>(G2); G3 += dppf<0x4E>(G3);                                     \
        G0 += PF.x; G1 += PF.y; G2 += PF.z; G3 += PF.w;                                 \
        float arg = q == 0 ? G0 : (q == 1 ? G1 : (q == 2 ? G2 : G3));                   \
        float act = __builtin_fmaf(mm, frcp(1.0f + fexp2(kmul * arg)), -dd);            \
        float gi = dppf<0x00>(act), gf = dppf<0x55>(act);                               \
        float gg = dppf<0xAA>(act), go = dppf<0xFF>(act);                               \
        cst = __builtin_fmaf(gf, cst, gi * gg);                                         \
        float th = __builtin_fmaf(2.0f, frcp(1.0f + fexp2(-2.885390082f * cst)), -1.0f);\
        float hnew = go * th;                                                           \
        if (q == 0) h0buf[WRP][u] = hnew;                                               \
        PF = gp[(ROWI) * 64];                                                           \
        barrier_nd();                                                                   \
    }

        A_STEP(pf0, 1, 0, 4)  // i = 0
#pragma unroll 1
        for (int b = 0; b < 1023; ++b) {  // i = 4b+1 .. 4b+4
            KEEP8(wA0_) KEEP8(wA1_) KEEP8(wA2_) KEEP8(wA3_)
            const int i4 = 4 * b;
            A_STEP(pf1, 0, 1, i4 + 5)
            A_STEP(pf2, 1, 0, i4 + 6)
            A_STEP(pf3, 0, 1, i4 + 7)
            A_STEP(pf0, 1, 0, (i4 + 8 < TT ? i4 + 8 : TT - 1))
        }
        A_STEP(pf1, 0, 1, TT - 1)  // i = 4093
        A_STEP(pf2, 1, 0, TT - 1)  // i = 4094
        A_STEP(pf3, 0, 1, TT - 1)  // i = 4095
        barrier_nd();              // i = 4096 (B-only step)
    } else {
        // ================= group B: layer 1 =================
        WDECL(wi0_) WDECL(wi1_) WDECL(wi2_) WDECL(wi3_)
        WDECL(wh0_) WDECL(wh1_) WDECL(wh2_) WDECL(wh3_)
        WLOAD(wi0_, w_ih1 + (0 * 64 + u) * 64 + qk)
        WLOAD(wi1_, w_ih1 + (1 * 64 + u) * 64 + qk)
        WLOAD(wi2_, w_ih1 + (2 * 64 + u) * 64 + qk)
        WLOAD(wi3_, w_ih1 + (3 * 64 + u) * 64 + qk)
        WLOAD(wh0_, w_hh1 + (0 * 64 + u) * 64 + qk)
        WLOAD(wh1_, w_hh1 + (1 * 64 + u) * 64 + qk)
        WLOAD(wh2_, w_hh1 + (2 * 64 + u) * 64 + qk)
        WLOAD(wh3_, w_hh1 + (3 * 64 + u) * 64 + qk)
        float4 bias;
        bias.x = b_ih1[0 * 64 + u] + b_hh1[0 * 64 + u];
        bias.y = b_ih1[1 * 64 + u] + b_hh1[1 * 64 + u];
        bias.z = b_ih1[2 * 64 + u] + b_hh1[2 * 64 + u];
        bias.w = b_ih1[3 * 64 + u] + b_hh1[3 * 64 + u];
        float hlast = 0.0f;
        if (q == 0) h1buf[1][u] = 0.0f;
        barrier_nd();  // pairs with A init barrier
        barrier_nd();  // pairs with A's i=0 step

#define B_STEP(P)                                                                       \
    {                                                                                   \
        HREAD(h_, &h0buf[P][qk])                                                        \
        HREAD(k_, &h1buf[(P) ^ 1][qk])                                                  \
        v2f a0 = Z2, a1 = Z2, a2 = Z2, a3 = Z2;                                         \
        v2f c0 = Z2, c1 = Z2, c2 = Z2, c3 = Z2;                                         \
        WDOT(a0, wi0_, h_) WDOT(a1, wi1_, h_) WDOT(a2, wi2_, h_) WDOT(a3, wi3_, h_)     \
        WDOT(c0, wh0_, k_) WDOT(c1, wh1_, k_) WDOT(c2, wh2_, k_) WDOT(c3, wh3_, k_)     \
        float G0 = (a0.x + a0.y) + (c0.x + c0.y);                                       \
        float G1 = (a1.x + a1.y) + (c1.x + c1.y);                                       \
        float G2 = (a2.x + a2.y) + (c2.x + c2.y);                                       \
        float G3 = (a3.x + a3.y) + (c3.x + c3.y);                                       \
        G0 += dppf<0xB1>(G0); G1 += dppf<0xB1>(G1);                                     \
        G2 += dppf<0xB1>(G2); G3 += dppf<0xB1>(G3);                                     \
        G0 += dppf<0x4E>(G0); G1 += dppf<0x4E>(G1);                                     \
        G2 += dppf<0x4E>(G2); G3 += dppf<0x4E>(G3);                                     \
        G0 += bias.x; G1 += bias.y; G2 += bias.z; G3 += bias.w;                         \
        float arg = q == 0 ? G0 : (q == 1 ? G1 : (q == 2 ? G2 : G3));                   \
        float act = __builtin_fmaf(mm, frcp(1.0f + fexp2(kmul * arg)), -dd);            \
        float gi = dppf<0x00>(act), gf = dppf<0x55>(act);                               \
        float gg = dppf<0xAA>(act), go = dppf<0xFF>(act);                               \
        cst = __builtin_fmaf(gf, cst, gi * gg);                                         \
        float th = __builtin_fmaf(2.0f, frcp(1.0f + fexp2(-2.885390082f * cst)), -1.0f);\
        float hnew = go * th;                                                           \
        hlast = hnew;                                                                   \
        if (q == 0) h1buf[P][u] = hnew;                                                 \
        barrier_nd();                                                                   \
    }

#pragma unroll 1
        for (int b = 0; b < 1023; ++b) {
            KEEP8(wi0_) KEEP8(wi1_) KEEP8(wi2_) KEEP8(wi3_)
            KEEP8(wh0_) KEEP8(wh1_) KEEP8(wh2_) KEEP8(wh3_)
            asm volatile("" : "+v"(bias.x), "+v"(bias.y), "+v"(bias.z), "+v"(bias.w));
            B_STEP(0)
            B_STEP(1)
            B_STEP(0)
            B_STEP(1)
        }
        B_STEP(0)  // i = 4093
        B_STEP(1)  // i = 4094
        B_STEP(0)  // i = 4095
        B_STEP(1)  // i = 4096 -> h1_4095 (final)
        if (q == 0) {
            hc_out[u] = hlast;
            hc_out[64 + u] = cst;
        }
    }
}

// Kernel 3: out[0..800000) = c1 @ w_es.T + b_es ; out[800000..1.6M) = h1 @ w_eh.T + b_eh
__global__ __launch_bounds__(256) void proj_kernel(const float* __restrict__ hc,
                                                   const float* __restrict__ w_es,
                                                   const float* __restrict__ b_es,
                                                   const float* __restrict__ w_eh,
                                                   const float* __restrict__ b_eh,
                                                   float* __restrict__ out) {
    __shared__ __align__(16) float hv[64];
    __shared__ __align__(16) float cv[64];
    const int tid = threadIdx.x;
    if (tid < 64) hv[tid] = hc[tid];
    else if (tid < 128) cv[tid - 64] = hc[tid];
    __syncthreads();

    const int p = tid & 3;
    const long r = (long)blockIdx.x * 64 + (tid >> 2);
    const float* w;
    const float* bb;
    const float* v;
    long rr;
    if (r < DPROJ) {
        rr = r;
        w = w_es;
        bb = b_es;
        v = cv;
    } else {
        rr = r - DPROJ;
        w = w_eh;
        bb = b_eh;
        v = hv;
    }
    const float4* wp = (const float4*)(w + rr * 64 + p * 16);
    const float4* vp = (const float4*)(v + p * 16);
    v2f s = {0.0f, 0.0f};
#pragma unroll
    for (int cc = 0; cc < 4; ++cc) {
        float4 wv = wp[cc];
        float4 vv = vp[cc];
        v2f w01 = {wv.x, wv.y}, v01 = {vv.x, vv.y};
        v2f w23 = {wv.z, wv.w}, v23 = {vv.z, vv.w};
        s = pkfma(w01, v01, s);
        s = pkfma(w23, v23, s);
    }
    float sum = s.x + s.y;
    sum += dppf<0xB1>(sum);
    sum += dppf<0x4E>(sum);
    if (p == 0) out[r] = sum + bb[rr];
}

extern "C" void kernel_launch(void* const* d_in, const int* in_sizes, int n_in,
                              void* d_out, int out_size, void* d_ws, size_t ws_size,
                              hipStream_t stream) {
    const float* x = (const float*)d_in[0];
    const float* w_ih0 = (const float*)d_in[1];
    const float* w_hh0 = (const float*)d_in[2];
    const float* b_ih0 = (const float*)d_in[3];
    const float* b_hh0 = (const float*)d_in[4];
    const float* w_ih1 = (const float*)d_in[5];
    const float* w_hh1 = (const float*)d_in[6];
    const float* b_ih1 = (const float*)d_in[7];
    const float* b_hh1 = (const float*)d_in[8];
    const float* w_eh = (const float*)d_in[9];
    const float* b_eh = (const float*)d_in[10];
    const float* w_es = (const float*)d_in[11];
    const float* b_es = (const float*)d_in[12];
    float* out = (float*)d_out;

    float* gx0 = (float*)d_ws;     // 4096*256 floats = 4 MB (permuted float4-per-unit)
    float* hc = gx0 + 4096 * 256;  // 128 floats: [h1(64), c1(64)]

    gx0_kernel<<<4096, 256, 0, stream>>>(x, w_ih0, b_ih0, b_hh0, gx0);
    lstm_kernel<<<1, 512, 0, stream>>>(gx0, w_hh0, w_ih1, w_hh1, b_ih1, b_hh1, hc);
    proj_kernel<<<2 * DPROJ / 64, 256, 0, stream>>>(hc, w_es, b_es, w_eh, b_eh, out);
}

// Round 5
// 2324.508 us; speedup vs baseline: 1.0387x; 1.0133x over previous
//
#include <hip/hip_runtime.h>

#define TT 4096
#define DPROJ 800000

typedef float v2f __attribute__((ext_vector_type(2)));
typedef float v4f __attribute__((ext_vector_type(4)));

__device__ __forceinline__ float fexp2(float x) { return __builtin_amdgcn_exp2f(x); }
__device__ __forceinline__ float frcp(float x) { return __builtin_amdgcn_rcpf(x); }

__device__ __forceinline__ v2f pkfma(v2f a, v2f b, v2f c) {
    asm("v_pk_fma_f32 %0, %1, %2, %0" : "+v"(c) : "v"(a), "v"(b));
    return c;
}

template <int CTRL>
__device__ __forceinline__ float dppf(float x) {
    return __int_as_float(
        __builtin_amdgcn_update_dpp(0, __float_as_int(x), CTRL, 0xF, 0xF, true));
}

__device__ __forceinline__ v2f lo2(v4f v) { return __builtin_shufflevector(v, v, 0, 1); }
__device__ __forceinline__ v2f hi2(v4f v) { return __builtin_shufflevector(v, v, 2, 3); }

// barrier WITHOUT the vmcnt(0) drain __syncthreads would emit.
__device__ __forceinline__ void barrier_nd() {
    asm volatile("s_waitcnt lgkmcnt(0)\n\ts_barrier" ::: "memory");
}

// ---- named-register bundles (NO allocas -> NO scratch) ----
#define WDECL(nm) v2f nm##0, nm##1, nm##2, nm##3, nm##4, nm##5, nm##6, nm##7;
#define WLOAD(nm, base)                                                      \
    {                                                                        \
        const v4f* q_ = (const v4f*)(base);                                  \
        v4f A_ = q_[0], B_ = q_[1], C_ = q_[2], D_ = q_[3];                  \
        nm##0 = lo2(A_); nm##1 = hi2(A_); nm##2 = lo2(B_); nm##3 = hi2(B_);  \
        nm##4 = lo2(C_); nm##5 = hi2(C_); nm##6 = lo2(D_); nm##7 = hi2(D_);  \
    }
#define WDOT(acc, nm, h)                                                     \
    acc = pkfma(nm##0, h##0, acc); acc = pkfma(nm##1, h##1, acc);            \
    acc = pkfma(nm##2, h##2, acc); acc = pkfma(nm##3, h##3, acc);            \
    acc = pkfma(nm##4, h##4, acc); acc = pkfma(nm##5, h##5, acc);            \
    acc = pkfma(nm##6, h##6, acc); acc = pkfma(nm##7, h##7, acc);
#define HREAD(h, ptr)                                                        \
    v2f h##0, h##1, h##2, h##3, h##4, h##5, h##6, h##7;                      \
    {                                                                        \
        const v4f* p_ = (const v4f*)(ptr);                                   \
        v4f ha_ = p_[0], hb_ = p_[1], hc_ = p_[2], hd_ = p_[3];              \
        h##0 = lo2(ha_); h##1 = hi2(ha_); h##2 = lo2(hb_); h##3 = hi2(hb_);  \
        h##4 = lo2(hc_); h##5 = hi2(hc_); h##6 = lo2(hd_); h##7 = hi2(hd_);  \
    }

// Kernel 1: gx0p[t*256 + u*4 + g] = dot(x[t,:], w_ih0[g*64+u,:]) + b_ih0 + b_hh0
__global__ __launch_bounds__(256) void gx0_kernel(const float* __restrict__ x,
                                                  const float* __restrict__ w_ih0,
                                                  const float* __restrict__ b_ih0,
                                                  const float* __restrict__ b_hh0,
                                                  float* __restrict__ gx0p) {
    __shared__ __align__(16) float xs[32];
    const int t = blockIdx.x;
    const int j = threadIdx.x;
    if (j < 32) xs[j] = x[t * 32 + j];
    __syncthreads();
    const float4* w4 = (const float4*)(w_ih0 + j * 32);
    const float4* x4 = (const float4*)xs;
    float acc = b_ih0[j] + b_hh0[j];
#pragma unroll
    for (int u = 0; u < 8; ++u) {
        float4 w = w4[u];
        float4 xv = x4[u];
        acc += w.x * xv.x + w.y * xv.y + w.z * xv.z + w.w * xv.w;
    }
    const int g = j >> 6;
    const int uu = j & 63;
    gx0p[t * 256 + uu * 4 + g] = acc;
}

// Kernel 2: sequential 2-layer LSTM. 768 threads = 12 waves on 1 CU, 3 groups:
//   A (t<256):   layer0 recurrence, weights w_hh0 (64 regs/thread)
//   C (256-511): p(t) = w_ih1 . h0(t), one slot behind A (64 regs/thread)
//   B (512-767): layer1 recurrence, weights w_hh1 only + p from LDS (64 regs)
// Rationale (rounds 0-4): RA grants ~92 VGPRs regardless of every occupancy
// knob (waves_per_eu, launch_bounds, LDS pin, keep-alive asm), so the old
// B-group's ~200-reg live set was sunk/spilled into the 4096-step loop
// (~600+ cy/step).  gfx950 assembler rejects AGPR sources on VOP3P, so
// sourcing spills directly is impossible.  Fix: no thread needs more than
// ~120 live regs.  Pipeline lag 2; parity P=slot&1:
//   A: reads h0buf[P^1], writes h0buf[P]
//   C: reads h0buf[P^1], writes pbuf[P^1][u*4+gate]   (raw partial, no act)
//   B: reads pbuf[P] + h1buf[P^1], writes h1buf[P]
// Every group executes 1 init barrier + 4098 slot barriers.
__global__ __launch_bounds__(768, 3)
void lstm_kernel(const float* __restrict__ gx0,
                 const float* __restrict__ w_hh0,
                 const float* __restrict__ w_ih1,
                 const float* __restrict__ w_hh1,
                 const float* __restrict__ b_ih1,
                 const float* __restrict__ b_hh1,
                 float* __restrict__ hc_out) {
    // 96 KiB pin -> 1 WG/CU physically (proven harmless round 3).
    __shared__ __align__(16) float lds_pool[24576];
    float(*h0buf)[64] = (float(*)[64])(lds_pool);         // [2][64]
    float(*h1buf)[64] = (float(*)[64])(lds_pool + 128);   // [2][64]
    float(*pbuf)[256] = (float(*)[256])(lds_pool + 256);  // [2][256]

    const int t = threadIdx.x;
    const int g3 = t >> 8;
    const int j = t & 255;
    const int u = j >> 2;
    const int q = j & 3;
    const int qk = q * 16;
    const bool qg = (q == 2);
    const float kmul = qg ? -2.885390082f : -1.442695041f;
    const float mm = qg ? 2.0f : 1.0f;
    const float dd = qg ? 1.0f : 0.0f;
    const v2f Z2 = {0.0f, 0.0f};
    float cst = 0.0f;

    if (g3 == 0) {
        // ================= group A: layer 0 =================
        WDECL(wA0_) WDECL(wA1_) WDECL(wA2_) WDECL(wA3_)
        WLOAD(wA0_, w_hh0 + (0 * 64 + u) * 64 + qk)
        WLOAD(wA1_, w_hh0 + (1 * 64 + u) * 64 + qk)
        WLOAD(wA2_, w_hh0 + (2 * 64 + u) * 64 + qk)
        WLOAD(wA3_, w_hh0 + (3 * 64 + u) * 64 + qk)
        const float4* gp = ((const float4*)gx0) + u;
        float4 pf0 = gp[0 * 64];
        float4 pf1 = gp[1 * 64];
        float4 pf2 = gp[2 * 64];
        float4 pf3 = gp[3 * 64];
        if (q == 0) h0buf[1][u] = 0.0f;
        barrier_nd();  // init visible

#define A_STEP(PF, RDP, WRP, ROWI)                                                      \
    {                                                                                   \
        HREAD(h_, &h0buf[RDP][qk])                                                      \
        v2f a0 = Z2, a1 = Z2, a2 = Z2, a3 = Z2;                                         \
        WDOT(a0, wA0_, h_) WDOT(a1, wA1_, h_) WDOT(a2, wA2_, h_) WDOT(a3, wA3_, h_)     \
        float G0 = a0.x + a0.y, G1 = a1.x + a1.y, G2 = a2.x + a2.y, G3 = a3.x + a3.y;   \
        G0 += dppf<0xB1>(G0); G1 += dppf<0xB1>(G1);                                     \
        G2 += dppf<0xB1>(G2); G3 += dppf<0xB1>(G3);                                     \
        G0 += dppf<0x4E>(G0); G1 += dppf<0x4E>(G1);                                     \
        G2 += dppf<0x4E>(G2); G3 += dppf<0x4E>(G3);                                     \
        G0 += PF.x; G1 += PF.y; G2 += PF.z; G3 += PF.w;                                 \
        float arg = q == 0 ? G0 : (q == 1 ? G1 : (q == 2 ? G2 : G3));                   \
        float act = __builtin_fmaf(mm, frcp(1.0f + fexp2(kmul * arg)), -dd);            \
        float gi = dppf<0x00>(act), gf = dppf<0x55>(act);                               \
        float gg = dppf<0xAA>(act), go = dppf<0xFF>(act);                               \
        cst = __builtin_fmaf(gf, cst, gi * gg);                                         \
        float th = __builtin_fmaf(2.0f, frcp(1.0f + fexp2(-2.885390082f * cst)), -1.0f);\
        float hnew = go * th;                                                           \
        if (q == 0) h0buf[WRP][u] = hnew;                                               \
        PF = gp[(ROWI) * 64];                                                           \
        barrier_nd();                                                                   \
    }

        A_STEP(pf0, 1, 0, 4)  // slot 0
#pragma unroll 1
        for (int b = 0; b < 1023; ++b) {  // slots 4b+1 .. 4b+4
            const int i4 = 4 * b;
            A_STEP(pf1, 0, 1, i4 + 5)
            A_STEP(pf2, 1, 0, i4 + 6)
            A_STEP(pf3, 0, 1, i4 + 7)
            A_STEP(pf0, 1, 0, (i4 + 8 < TT ? i4 + 8 : TT - 1))
        }
        A_STEP(pf1, 0, 1, TT - 1)  // slot 4093
        A_STEP(pf2, 1, 0, TT - 1)  // slot 4094
        A_STEP(pf3, 0, 1, TT - 1)  // slot 4095
        barrier_nd();              // slot 4096 (C+B)
        barrier_nd();              // slot 4097 (B)
    } else if (g3 == 1) {
        // ================= group C: p = w_ih1 . h0 =================
        WDECL(wC0_) WDECL(wC1_) WDECL(wC2_) WDECL(wC3_)
        WLOAD(wC0_, w_ih1 + (0 * 64 + u) * 64 + qk)
        WLOAD(wC1_, w_ih1 + (1 * 64 + u) * 64 + qk)
        WLOAD(wC2_, w_ih1 + (2 * 64 + u) * 64 + qk)
        WLOAD(wC3_, w_ih1 + (3 * 64 + u) * 64 + qk)
        barrier_nd();  // init
        barrier_nd();  // slot 0 (A computes h0(0))

#define C_STEP(RD)                                                                      \
    {                                                                                   \
        HREAD(h_, &h0buf[RD][qk])                                                       \
        v2f a0 = Z2, a1 = Z2, a2 = Z2, a3 = Z2;                                         \
        WDOT(a0, wC0_, h_) WDOT(a1, wC1_, h_) WDOT(a2, wC2_, h_) WDOT(a3, wC3_, h_)     \
        float G0 = a0.x + a0.y, G1 = a1.x + a1.y, G2 = a2.x + a2.y, G3 = a3.x + a3.y;   \
        G0 += dppf<0xB1>(G0); G1 += dppf<0xB1>(G1);                                     \
        G2 += dppf<0xB1>(G2); G3 += dppf<0xB1>(G3);                                     \
        G0 += dppf<0x4E>(G0); G1 += dppf<0x4E>(G1);                                     \
        G2 += dppf<0x4E>(G2); G3 += dppf<0x4E>(G3);                                     \
        float val = q == 0 ? G0 : (q == 1 ? G1 : (q == 2 ? G2 : G3));                   \
        pbuf[RD][j] = val;                                                              \
        barrier_nd();                                                                   \
    }

#pragma unroll 1
        for (int b = 0; b < 1024; ++b) {  // slots 1..4096
            C_STEP(0)
            C_STEP(1)
            C_STEP(0)
            C_STEP(1)
        }
        barrier_nd();  // slot 4097 (B)
    } else {
        // ================= group B: layer 1 recurrence =================
        WDECL(wh0_) WDECL(wh1_) WDECL(wh2_) WDECL(wh3_)
        WLOAD(wh0_, w_hh1 + (0 * 64 + u) * 64 + qk)
        WLOAD(wh1_, w_hh1 + (1 * 64 + u) * 64 + qk)
        WLOAD(wh2_, w_hh1 + (2 * 64 + u) * 64 + qk)
        WLOAD(wh3_, w_hh1 + (3 * 64 + u) * 64 + qk)
        const float biasq = b_ih1[q * 64 + u] + b_hh1[q * 64 + u];
        float hlast = 0.0f;
        if (q == 0) h1buf[1][u] = 0.0f;
        barrier_nd();  // init
        barrier_nd();  // slot 0
        barrier_nd();  // slot 1

#define B_STEP(P)                                                                       \
    {                                                                                   \
        HREAD(k_, &h1buf[(P) ^ 1][qk])                                                  \
        float pv = pbuf[P][j];                                                          \
        v2f c0 = Z2, c1 = Z2, c2 = Z2, c3 = Z2;                                         \
        WDOT(c0, wh0_, k_) WDOT(c1, wh1_, k_) WDOT(c2, wh2_, k_) WDOT(c3, wh3_, k_)     \
        float G0 = c0.x + c0.y, G1 = c1.x + c1.y, G2 = c2.x + c2.y, G3 = c3.x + c3.y;   \
        G0 += dppf<0xB1>(G0); G1 += dppf<0xB1>(G1);                                     \
        G2 += dppf<0xB1>(G2); G3 += dppf<0xB1>(G3);                                     \
        G0 += dppf<0x4E>(G0); G1 += dppf<0x4E>(G1);                                     \
        G2 += dppf<0x4E>(G2); G3 += dppf<0x4E>(G3);                                     \
        float arg = (q == 0 ? G0 : (q == 1 ? G1 : (q == 2 ? G2 : G3))) + pv + biasq;    \
        float act = __builtin_fmaf(mm, frcp(1.0f + fexp2(kmul * arg)), -dd);            \
        float gi = dppf<0x00>(act), gf = dppf<0x55>(act);                               \
        float gg = dppf<0xAA>(act), go = dppf<0xFF>(act);                               \
        cst = __builtin_fmaf(gf, cst, gi * gg);                                         \
        float th = __builtin_fmaf(2.0f, frcp(1.0f + fexp2(-2.885390082f * cst)), -1.0f);\
        float hnew = go * th;                                                           \
        hlast = hnew;                                                                   \
        if (q == 0) h1buf[P][u] = hnew;                                                 \
        barrier_nd();                                                                   \
    }

#pragma unroll 1
        for (int b = 0; b < 1024; ++b) {  // slots 2..4097
            B_STEP(0)
            B_STEP(1)
            B_STEP(0)
            B_STEP(1)
        }
        if (q == 0) {
            hc_out[u] = hlast;
            hc_out[64 + u] = cst;
        }
    }
}

// Kernel 3: out[0..800000) = c1 @ w_es.T + b_es ; out[800000..1.6M) = h1 @ w_eh.T + b_eh
__global__ __launch_bounds__(256) void proj_kernel(const float* __restrict__ hc,
                                                   const float* __restrict__ w_es,
                                                   const float* __restrict__ b_es,
                                                   const float* __restrict__ w_eh,
                                                   const float* __restrict__ b_eh,
                                                   float* __restrict__ out) {
    __shared__ __align__(16) float hv[64];
    __shared__ __align__(16) float cv[64];
    const int tid = threadIdx.x;
    if (tid < 64) hv[tid] = hc[tid];
    else if (tid < 128) cv[tid - 64] = hc[tid];
    __syncthreads();

    const int p = tid & 3;
    const long r = (long)blockIdx.x * 64 + (tid >> 2);
    const float* w;
    const float* bb;
    const float* v;
    long rr;
    if (r < DPROJ) {
        rr = r;
        w = w_es;
        bb = b_es;
        v = cv;
    } else {
        rr = r - DPROJ;
        w = w_eh;
        bb = b_eh;
        v = hv;
    }
    const float4* wp = (const float4*)(w + rr * 64 + p * 16);
    const float4* vp = (const float4*)(v + p * 16);
    v2f s = {0.0f, 0.0f};
#pragma unroll
    for (int cc = 0; cc < 4; ++cc) {
        float4 wv = wp[cc];
        float4 vv = vp[cc];
        v2f w01 = {wv.x, wv.y}, v01 = {vv.x, vv.y};
        v2f w23 = {wv.z, wv.w}, v23 = {vv.z, vv.w};
        s = pkfma(w01, v01, s);
        s = pkfma(w23, v23, s);
    }
    float sum = s.x + s.y;
    sum += dppf<0xB1>(sum);
    sum += dppf<0x4E>(sum);
    if (p == 0) out[r] = sum + bb[rr];
}

extern "C" void kernel_launch(void* const* d_in, const int* in_sizes, int n_in,
                              void* d_out, int out_size, void* d_ws, size_t ws_size,
                              hipStream_t stream) {
    const float* x = (const float*)d_in[0];
    const float* w_ih0 = (const float*)d_in[1];
    const float* w_hh0 = (const float*)d_in[2];
    const float* b_ih0 = (const float*)d_in[3];
    const float* b_hh0 = (const float*)d_in[4];
    const float* w_ih1 = (const float*)d_in[5];
    const float* w_hh1 = (const float*)d_in[6];
    const float* b_ih1 = (const float*)d_in[7];
    const float* b_hh1 = (const float*)d_in[8];
    const float* w_eh = (const float*)d_in[9];
    const float* b_eh = (const float*)d_in[10];
    const float* w_es = (const float*)d_in[11];
    const float* b_es = (const float*)d_in[12];
    float* out = (float*)d_out;

    float* gx0 = (float*)d_ws;     // 4096*256 floats = 4 MB (permuted float4-per-unit)
    float* hc = gx0 + 4096 * 256;  // 128 floats: [h1(64), c1(64)]

    gx0_kernel<<<4096, 256, 0, stream>>>(x, w_ih0, b_ih0, b_hh0, gx0);
    lstm_kernel<<<1, 768, 0, stream>>>(gx0, w_hh0, w_ih1, w_hh1, b_ih1, b_hh1, hc);
    proj_kernel<<<2 * DPROJ / 64, 256, 0, stream>>>(hc, w_es, b_es, w_eh, b_eh, out);
}